// Round 6
// baseline (441.189 us; speedup 1.0000x reference)
//
#include <hip/hip_runtime.h>
#include <stdint.h>

typedef unsigned short u16;
typedef unsigned int   u32;

#define N_NODES 30000
#define N_EDGES 60000
#define A_DEG   6
#define D_DEG   16
#define BATCH   4096
#define FEAT    256

// ---------- bf16 helpers (ws intermediates are bf16; all I/O is f32) ----------
__device__ __forceinline__ float bfbits2f(u32 hi){ union{u32 u; float f;} v; v.u = hi; return v.f; }
__device__ __forceinline__ float bf2f(u16 h){ return bfbits2f(((u32)h)<<16); }
__device__ __forceinline__ u16 f2bf(float f){
  union{float f; u32 u;} v; v.f = f;
  u32 u = v.u;
  return (u16)((u + 0x7fffu + ((u>>16)&1u)) >> 16);   // RTNE
}

struct F4 { float x,y,z,w; };

__device__ __forceinline__ F4 load4(const float* p){
  float4 t = *reinterpret_cast<const float4*>(p);
  F4 f; f.x=t.x; f.y=t.y; f.z=t.z; f.w=t.w; return f;
}
__device__ __forceinline__ F4 load4(const u16* p){
  uint2 u = *reinterpret_cast<const uint2*>(p);
  F4 f;
  f.x = bfbits2f(u.x<<16);
  f.y = bfbits2f(u.x & 0xffff0000u);
  f.z = bfbits2f(u.y<<16);
  f.w = bfbits2f(u.y & 0xffff0000u);
  return f;
}
__device__ __forceinline__ void store_bf4(u16* p, F4 f){
  uint2 u;
  u.x = (u32)f2bf(f.x) | ((u32)f2bf(f.y)<<16);
  u.y = (u32)f2bf(f.z) | ((u32)f2bf(f.w)<<16);
  *reinterpret_cast<uint2*>(p) = u;
}

__device__ __forceinline__ float eluf(float x){ return x > 0.f ? x : (__expf(x) - 1.f); }
__device__ __forceinline__ float lrelu(float x){ return x > 0.f ? x : 0.2f*x; }

__device__ __forceinline__ float wave_sum(float v){
  #pragma unroll
  for (int off = 32; off > 0; off >>= 1) v += __shfl_down(v, off, 64);
  return v;
}

// ---------- GEMM: Y[M,256] = act(X[M,256]) @ W[256,256] -> bf16 ----------
template<typename TIN, bool ELU>
__global__ __launch_bounds__(256) void gemm_k(const TIN* __restrict__ X,
                                              const float* __restrict__ W,
                                              u16* __restrict__ Y)
{
  __shared__ float Xs[16][FEAT];
  const int tid = threadIdx.x;
  const long row0 = (long)blockIdx.x * 16;

  {
    const int r = tid >> 4;
    const int c = (tid & 15) << 4;
    const TIN* src = X + (row0 + r)*FEAT + c;
    float* dst = &Xs[r][c];
    #pragma unroll
    for (int i=0;i<4;i++){
      F4 v = load4(src + 4*i);
      if (ELU){ v.x=eluf(v.x); v.y=eluf(v.y); v.z=eluf(v.z); v.w=eluf(v.w); }
      dst[4*i+0]=v.x; dst[4*i+1]=v.y; dst[4*i+2]=v.z; dst[4*i+3]=v.w;
    }
  }
  __syncthreads();

  const int r0 = (tid >> 6) * 4;
  const int cb = (tid & 63) * 4;
  float acc[4][4] = {};

  for (int k = 0; k < FEAT; k += 4){
    float xv[4][4];
    #pragma unroll
    for (int r=0;r<4;r++){
      float4 t = *reinterpret_cast<const float4*>(&Xs[r0+r][k]);
      xv[r][0]=t.x; xv[r][1]=t.y; xv[r][2]=t.z; xv[r][3]=t.w;
    }
    #pragma unroll
    for (int kk=0;kk<4;kk++){
      F4 wv = load4(W + (long)(k+kk)*FEAT + cb);
      #pragma unroll
      for (int r=0;r<4;r++){
        acc[r][0] += xv[r][kk]*wv.x;
        acc[r][1] += xv[r][kk]*wv.y;
        acc[r][2] += xv[r][kk]*wv.z;
        acc[r][3] += xv[r][kk]*wv.w;
      }
    }
  }

  #pragma unroll
  for (int r=0;r<4;r++){
    F4 o; o.x=acc[r][0]; o.y=acc[r][1]; o.z=acc[r][2]; o.w=acc[r][3];
    store_bf4(Y + (row0 + r0 + r)*FEAT + cb, o);
  }
}

// ---------- wvec: wE[row] = W[row,:] · a[:]  (f32 in/out, 256 rows) ----------
__global__ __launch_bounds__(256) void wvec_k(const float* __restrict__ W,
    const float* __restrict__ a, float* __restrict__ wE)
{
  const int lane = threadIdx.x & 63;
  const int row  = blockIdx.x*4 + (threadIdx.x >> 6);
  const int c = lane*4;
  F4 h = load4(W + (long)row*FEAT + c);
  F4 v = load4(a + c);
  float p = h.x*v.x + h.y*v.y + h.z*v.z + h.w*v.w;
  p = wave_sum(p);
  if (lane == 0) wE[row] = p;
}

// ---------- per-row double dot (bf16 H, f32 vectors) ----------
__global__ __launch_bounds__(256) void rowdot2_k(const u16* __restrict__ H,
    const float* __restrict__ v1, const float* __restrict__ v2,
    float* __restrict__ d1, float* __restrict__ d2)
{
  const int lane = threadIdx.x & 63;
  const int row  = blockIdx.x*4 + (threadIdx.x >> 6);
  const int c = lane*4;
  F4 h = load4(H + (long)row*FEAT + c);
  F4 a = load4(v1 + c);
  F4 b = load4(v2 + c);
  float p1 = h.x*a.x + h.y*a.y + h.z*a.z + h.w*a.w;
  float p2 = h.x*b.x + h.y*b.y + h.z*b.z + h.w*b.w;
  p1 = wave_sum(p1);
  p2 = wave_sum(p2);
  if (lane == 0){ d1[row] = p1; d2[row] = p2; }
}

// ---------- matvec: d[row] = act(X[row]) · w ----------
template<typename TIN, bool ELU>
__global__ __launch_bounds__(256) void matvec_k(const TIN* __restrict__ X,
    const float* __restrict__ w, float* __restrict__ d)
{
  const int lane = threadIdx.x & 63;
  const int row  = blockIdx.x*4 + (threadIdx.x >> 6);
  const int c = lane*4;
  F4 h = load4(X + (long)row*FEAT + c);
  if (ELU){ h.x = eluf(h.x); h.y = eluf(h.y); h.z = eluf(h.z); h.w = eluf(h.w); }
  float4 a = *reinterpret_cast<const float4*>(w + c);
  float p = h.x*a.x + h.y*a.y + h.z*a.z + h.w*a.w;
  p = wave_sum(p);
  if (lane == 0) d[row] = p;
}

// ---------- edge attention: softmax over A=6 member nodes ----------
__global__ __launch_bounds__(256) void edge_attn_k(const u16* __restrict__ Hn,
    const int* __restrict__ edge_list, const float* __restrict__ seb,
    const float* __restrict__ hg, const float* __restrict__ an_hi,
    u16* __restrict__ NE, float* __restrict__ ned)
{
  const int lane = threadIdx.x & 63;
  const int e = blockIdx.x*4 + (threadIdx.x >> 6);
  int idx[A_DEG];
  float w[A_DEG];
  const float sb = seb[e];
  float mx = -1e30f;
  #pragma unroll
  for (int a=0;a<A_DEG;a++){
    idx[a] = edge_list[e*A_DEG + a];
    float s = lrelu(sb + hg[idx[a]]);
    w[a] = s; mx = fmaxf(mx, s);
  }
  float sum = 0.f;
  #pragma unroll
  for (int a=0;a<A_DEG;a++){ w[a] = __expf(w[a]-mx); sum += w[a]; }
  const float inv = 1.f/sum;

  const int c = lane*4;
  float ax=0,ay=0,az=0,aw=0;
  #pragma unroll
  for (int a=0;a<A_DEG;a++){
    F4 h = load4(Hn + (long)idx[a]*FEAT + c);
    float ww = w[a]*inv;
    ax += ww*h.x; ay += ww*h.y; az += ww*h.z; aw += ww*h.w;
  }
  F4 o; o.x=ax; o.y=ay; o.z=az; o.w=aw;
  store_bf4(NE + (long)e*FEAT + c, o);

  F4 v = load4(an_hi + c);
  float p = ax*v.x + ay*v.y + az*v.z + aw*v.w;
  p = wave_sum(p);
  if (lane == 0) ned[e] = p;
}

// ---------- node attention: softmax over D=16 incident hyperedges ----------
__global__ __launch_bounds__(256) void node_attn_k(const u16* __restrict__ NE,
    const int* __restrict__ node_list, const float* __restrict__ snb,
    const float* __restrict__ ned, u16* __restrict__ NNo)
{
  const int lane = threadIdx.x & 63;
  const int n = blockIdx.x*4 + (threadIdx.x >> 6);
  int idx[D_DEG];
  float w[D_DEG];
  const float sb = snb[n];
  float mx = -1e30f;
  #pragma unroll
  for (int d=0; d<D_DEG; d++){
    idx[d] = node_list[n*D_DEG + d];
    float s = lrelu(sb + ned[idx[d]]);
    w[d] = s; mx = fmaxf(mx, s);
  }
  float sum = 0.f;
  #pragma unroll
  for (int d=0; d<D_DEG; d++){ w[d] = __expf(w[d]-mx); sum += w[d]; }
  const float inv = 1.f/sum;

  const int c = lane*4;
  float ax=0,ay=0,az=0,aw=0;
  #pragma unroll
  for (int d=0; d<D_DEG; d++){
    F4 h = load4(NE + (long)idx[d]*FEAT + c);
    float ww = w[d]*inv;
    ax += ww*h.x; ay += ww*h.y; az += ww*h.z; aw += ww*h.w;
  }
  F4 o; o.x=ax; o.y=ay; o.z=az; o.w=aw;
  store_bf4(NNo + (long)n*FEAT + c, o);
}

// ---------- final batch assembly — F32 OUTPUT ----------
__global__ __launch_bounds__(256) void assemble_k(const u16* __restrict__ NNo,
    const u16* __restrict__ NE, const int* __restrict__ batch, float* __restrict__ out)
{
  const int b = blockIdx.x;
  const int j = threadIdx.x;
  int bi[7];
  #pragma unroll
  for (int s=0;s<7;s++) bi[s] = batch[b*7 + s];
  int right = 0;
  #pragma unroll
  for (int c=0;c<6;c++) if (bi[c] != 0) right = c+1;

  // slot 0: hyperedge embedding
  out[((long)b*7 + 0)*FEAT + j] = eluf(bf2f(NE[(long)bi[0]*FEAT + j]));

  #pragma unroll
  for (int s=1;s<7;s++){
    float val = 0.f;
    if (s < right) val = eluf(bf2f(NNo[(long)bi[s]*FEAT + j]));
    out[((long)b*7 + s)*FEAT + j] = val;
  }
}

extern "C" void kernel_launch(void* const* d_in, const int* in_sizes, int n_in,
                              void* d_out, int out_size, void* d_ws, size_t ws_size,
                              hipStream_t stream)
{
  const int*   batch      = (const int*)d_in[0];
  const float* node_embs  = (const float*)d_in[1];
  const float* edge_embs  = (const float*)d_in[2];
  const int*   edge_list  = (const int*)d_in[3];
  const int*   node_list  = (const int*)d_in[4];
  const float* Wn1 = (const float*)d_in[5];
  const float* We1 = (const float*)d_in[6];
  const float* ae1 = (const float*)d_in[7];
  const float* an1 = (const float*)d_in[8];
  const float* Wn2 = (const float*)d_in[9];
  const float* We2 = (const float*)d_in[10];
  const float* ae2 = (const float*)d_in[11];
  const float* an2 = (const float*)d_in[12];
  float* out = (float*)d_out;

  char* ws = (char*)d_ws;
  size_t off = 0;
  auto alloc = [&](size_t bytes)->void* {
    void* p = ws + off; off += (bytes + 255) & ~(size_t)255; return p;
  };
  // ~62.2 MB (He never materialized: (x@We)·ae_lo == x·(We@ae_lo))
  u16* bHn = (u16*)alloc((size_t)N_NODES*FEAT*2);
  u16* bNE = (u16*)alloc((size_t)N_EDGES*FEAT*2);
  u16* bNN = (u16*)alloc((size_t)N_NODES*FEAT*2);
  float* hg  = (float*)alloc((size_t)N_NODES*4);
  float* snb = (float*)alloc((size_t)N_NODES*4);
  float* seb = (float*)alloc((size_t)N_EDGES*4);
  float* ned = (float*)alloc((size_t)N_EDGES*4);
  float* wE  = (float*)alloc(FEAT*4);

  dim3 blk(256);

  // ---- layer 1 (f32 inputs) ----
  wvec_k<<<FEAT/4, blk, 0, stream>>>(We1, ae1, wE);                              // wE = We1 @ ae1_lo
  gemm_k<float,false><<<N_NODES/16, blk, 0, stream>>>(node_embs, Wn1, bHn);      // Hn1
  rowdot2_k<<<N_NODES/4, blk, 0, stream>>>(bHn, ae1+FEAT, an1, hg, snb);         // hn·ae_hi, hn·an_lo
  matvec_k<float,false><<<N_EDGES/4, blk, 0, stream>>>(edge_embs, wE, seb);      // seb = x_e · wE
  edge_attn_k<<<N_EDGES/4, blk, 0, stream>>>(bHn, edge_list, seb, hg, an1+FEAT, bNE, ned);
  node_attn_k<<<N_NODES/4, blk, 0, stream>>>(bNE, node_list, snb, ned, bNN);

  // ---- layer 2 (ELU fused on loads) ----
  wvec_k<<<FEAT/4, blk, 0, stream>>>(We2, ae2, wE);                              // wE = We2 @ ae2_lo
  matvec_k<u16,true><<<N_EDGES/4, blk, 0, stream>>>(bNE, wE, seb);               // seb2 = elu(NE1)·wE (before NE overwrite)
  gemm_k<u16,true><<<N_NODES/16, blk, 0, stream>>>(bNN, Wn2, bHn);               // Hn2 = elu(NN1)@Wn2
  rowdot2_k<<<N_NODES/4, blk, 0, stream>>>(bHn, ae2+FEAT, an2, hg, snb);
  edge_attn_k<<<N_EDGES/4, blk, 0, stream>>>(bHn, edge_list, seb, hg, an2+FEAT, bNE, ned);
  node_attn_k<<<N_NODES/4, blk, 0, stream>>>(bNE, node_list, snb, ned, bNN);

  // ---- batch assembly (ELU on read, f32 out) ----
  assemble_k<<<BATCH, blk, 0, stream>>>(bNN, bNE, batch, out);
}

// Round 7
// 355.139 us; speedup vs baseline: 1.2423x; 1.2423x over previous
//
#include <hip/hip_runtime.h>
#include <stdint.h>

typedef unsigned short u16;
typedef unsigned int   u32;
typedef __attribute__((ext_vector_type(8))) short bf16x8;   // 8 bf16 (4 VGPRs)
typedef __attribute__((ext_vector_type(4))) float f32x4;    // MFMA C/D

#define N_NODES 30000
#define N_EDGES 60000
#define A_DEG   6
#define D_DEG   16
#define BATCH   4096
#define FEAT    256
#define APAD    8     // LDS pad (keeps 16B alignment: (256+8)*2 = 528 = 33*16)

// ---------- bf16 helpers ----------
__device__ __forceinline__ float bfbits2f(u32 hi){ union{u32 u; float f;} v; v.u = hi; return v.f; }
__device__ __forceinline__ float bf2f(u16 h){ return bfbits2f(((u32)h)<<16); }
__device__ __forceinline__ u16 f2bf(float f){
  union{float f; u32 u;} v; v.f = f;
  u32 u = v.u;
  return (u16)((u + 0x7fffu + ((u>>16)&1u)) >> 16);   // RTNE
}

struct F4 { float x,y,z,w; };

__device__ __forceinline__ F4 load4(const float* p){
  float4 t = *reinterpret_cast<const float4*>(p);
  F4 f; f.x=t.x; f.y=t.y; f.z=t.z; f.w=t.w; return f;
}
__device__ __forceinline__ F4 load4(const u16* p){
  uint2 u = *reinterpret_cast<const uint2*>(p);
  F4 f;
  f.x = bfbits2f(u.x<<16);
  f.y = bfbits2f(u.x & 0xffff0000u);
  f.z = bfbits2f(u.y<<16);
  f.w = bfbits2f(u.y & 0xffff0000u);
  return f;
}
__device__ __forceinline__ void store_bf4(u16* p, F4 f){
  uint2 u;
  u.x = (u32)f2bf(f.x) | ((u32)f2bf(f.y)<<16);
  u.y = (u32)f2bf(f.z) | ((u32)f2bf(f.w)<<16);
  *reinterpret_cast<uint2*>(p) = u;
}

__device__ __forceinline__ float eluf(float x){ return x > 0.f ? x : (__expf(x) - 1.f); }
__device__ __forceinline__ float lrelu(float x){ return x > 0.f ? x : 0.2f*x; }

__device__ __forceinline__ float wave_sum_lane0(float v){
  #pragma unroll
  for (int off = 32; off > 0; off >>= 1) v += __shfl_down(v, off, 64);
  return v;   // valid in lane 0
}
__device__ __forceinline__ float wave_sum_all(float v){
  #pragma unroll
  for (int off = 1; off < 64; off <<= 1) v += __shfl_xor(v, off, 64);
  return v;   // valid in all lanes
}

// ---------- weight transpose: Wt[n][k] = bf16(W[k][n]), 256x256 ----------
__global__ __launch_bounds__(256) void wtrans_k(const float* __restrict__ W,
                                                u16* __restrict__ Wt)
{
  __shared__ float T[32][33];
  const int bx = blockIdx.x;   // k-tile
  const int by = blockIdx.y;   // n-tile
  const int tc = threadIdx.x & 31;
  const int tr = threadIdx.x >> 5;       // 0..7
  #pragma unroll
  for (int i=0;i<4;i++){
    int r = tr + i*8;
    T[r][tc] = W[(bx*32 + r)*FEAT + by*32 + tc];
  }
  __syncthreads();
  #pragma unroll
  for (int i=0;i<4;i++){
    int r = tr + i*8;
    Wt[(by*32 + r)*FEAT + bx*32 + tc] = f2bf(T[tc][r]);
  }
}

// ---------- MFMA GEMM + fused rowdots ----------
// Y[M,256](bf16) = act(X[M,256]) @ W, via Wt[n][k] bf16.
// Also: hg[row] = Y[row]·v1, snb[row] = Y[row]·v2 (f32 accumulation).
// Block: 256 threads = 4 waves; tile 16 rows x 256 cols; wave w covers cols [w*64, w*64+64).
template<bool ELU, typename TIN>
__global__ __launch_bounds__(256) void gemm_mfma_k(
    const TIN* __restrict__ X, const u16* __restrict__ Wt,
    const float* __restrict__ v1, const float* __restrict__ v2,
    u16* __restrict__ Y, float* __restrict__ hg, float* __restrict__ snb)
{
  __shared__ u16 As[16][FEAT + APAD];
  __shared__ float hgs[16], sns[16];
  const int tid = threadIdx.x;
  const long row0 = (long)blockIdx.x * 16;

  if (tid < 16){ hgs[tid] = 0.f; sns[tid] = 0.f; }

  // stage X tile -> bf16 LDS (16 elems/thread)
  {
    const int r = tid >> 4;
    const int c = (tid & 15) << 4;
    const TIN* src = X + (row0 + r)*FEAT + c;
    u16* dst = &As[r][c];
    #pragma unroll
    for (int i=0;i<4;i++){
      F4 v = load4(src + 4*i);
      if (ELU){ v.x=eluf(v.x); v.y=eluf(v.y); v.z=eluf(v.z); v.w=eluf(v.w); }
      dst[4*i+0]=f2bf(v.x); dst[4*i+1]=f2bf(v.y);
      dst[4*i+2]=f2bf(v.z); dst[4*i+3]=f2bf(v.w);
    }
  }
  __syncthreads();

  const int wave = tid >> 6;
  const int lane = tid & 63;
  const int l15  = lane & 15;
  const int kg   = lane >> 4;          // k-group 0..3

  f32x4 acc[4] = {};                   // 4 n-tiles of 16 cols

  for (int k0 = 0; k0 < FEAT; k0 += 32){
    bf16x8 a = *reinterpret_cast<const bf16x8*>(&As[l15][k0 + kg*8]);
    #pragma unroll
    for (int t=0;t<4;t++){
      const int n = wave*64 + t*16 + l15;
      bf16x8 b = *reinterpret_cast<const bf16x8*>(Wt + (long)n*FEAT + k0 + kg*8);
      acc[t] = __builtin_amdgcn_mfma_f32_16x16x32_bf16(a, b, acc[t], 0, 0, 0);
    }
  }

  __syncthreads();   // A-tile reads done; reuse As for output staging

  // epilogue: stage Y tile + fused rowdots
  // C/D layout: col = lane&15 (+tile base), row = (lane>>4)*4 + reg
  float p1[4] = {0.f,0.f,0.f,0.f};
  float p2[4] = {0.f,0.f,0.f,0.f};
  #pragma unroll
  for (int t=0;t<4;t++){
    const int col = wave*64 + t*16 + l15;
    const float a1 = v1[col];
    const float a2 = v2[col];
    #pragma unroll
    for (int r=0;r<4;r++){
      const float val = acc[t][r];
      As[kg*4 + r][col] = f2bf(val);
      p1[r] += val * a1;
      p2[r] += val * a2;
    }
  }
  // reduce across the 16 lanes of the quad (same lane>>4)
  #pragma unroll
  for (int off=1; off<16; off<<=1){
    #pragma unroll
    for (int r=0;r<4;r++){
      p1[r] += __shfl_xor(p1[r], off, 64);
      p2[r] += __shfl_xor(p2[r], off, 64);
    }
  }
  if (l15 == 0){
    #pragma unroll
    for (int r=0;r<4;r++){
      atomicAdd(&hgs[kg*4 + r], p1[r]);
      atomicAdd(&sns[kg*4 + r], p2[r]);
    }
  }
  __syncthreads();

  // coalesced store of Y tile
  {
    const int r = tid >> 4;
    const int c = (tid & 15) << 4;
    const uint4* s = reinterpret_cast<const uint4*>(&As[r][c]);
    uint4* d = reinterpret_cast<uint4*>(Y + (row0 + r)*FEAT + c);
    d[0] = s[0]; d[1] = s[1];
  }
  if (tid < 16){
    hg[row0 + tid]  = hgs[tid];
    snb[row0 + tid] = sns[tid];
  }
}

// ---------- wvec: wE[row] = W[row,:] · a[:]  (f32, 256 rows) ----------
__global__ __launch_bounds__(256) void wvec_k(const float* __restrict__ W,
    const float* __restrict__ a, float* __restrict__ wE)
{
  const int lane = threadIdx.x & 63;
  const int row  = blockIdx.x*4 + (threadIdx.x >> 6);
  const int c = lane*4;
  F4 h = load4(W + (long)row*FEAT + c);
  F4 v = load4(a + c);
  float p = h.x*v.x + h.y*v.y + h.z*v.z + h.w*v.w;
  p = wave_sum_lane0(p);
  if (lane == 0) wE[row] = p;
}

// ---------- edge attention (fused seb): softmax over A=6 member nodes ----------
// seb = act(Xe[e]) · wE computed in-wave (Xe row e is only read by this wave,
// and written -- as NE -- only by this wave afterwards).
template<typename TIN, bool ELU>
__global__ __launch_bounds__(256) void edge_attn_k(const u16* __restrict__ Hn,
    const TIN* __restrict__ Xe, const float* __restrict__ wE,
    const int* __restrict__ edge_list,
    const float* __restrict__ hg, const float* __restrict__ an_hi,
    u16* __restrict__ NE, float* __restrict__ ned)
{
  const int lane = threadIdx.x & 63;
  const int e = blockIdx.x*4 + (threadIdx.x >> 6);
  const int c = lane*4;

  // fused seb
  float sb;
  {
    F4 x = load4(Xe + (long)e*FEAT + c);
    if (ELU){ x.x=eluf(x.x); x.y=eluf(x.y); x.z=eluf(x.z); x.w=eluf(x.w); }
    F4 v = load4(wE + c);
    sb = wave_sum_all(x.x*v.x + x.y*v.y + x.z*v.z + x.w*v.w);
  }

  int idx[A_DEG];
  float w[A_DEG];
  float mx = -1e30f;
  #pragma unroll
  for (int a=0;a<A_DEG;a++){
    idx[a] = edge_list[e*A_DEG + a];
    float s = lrelu(sb + hg[idx[a]]);
    w[a] = s; mx = fmaxf(mx, s);
  }
  float sum = 0.f;
  #pragma unroll
  for (int a=0;a<A_DEG;a++){ w[a] = __expf(w[a]-mx); sum += w[a]; }
  const float inv = 1.f/sum;

  float ax=0,ay=0,az=0,aw=0;
  #pragma unroll
  for (int a=0;a<A_DEG;a++){
    F4 h = load4(Hn + (long)idx[a]*FEAT + c);
    float ww = w[a]*inv;
    ax += ww*h.x; ay += ww*h.y; az += ww*h.z; aw += ww*h.w;
  }
  F4 o; o.x=ax; o.y=ay; o.z=az; o.w=aw;
  store_bf4(NE + (long)e*FEAT + c, o);

  F4 v = load4(an_hi + c);
  float p = wave_sum_lane0(ax*v.x + ay*v.y + az*v.z + aw*v.w);
  if (lane == 0) ned[e] = p;
}

// ---------- node attention: softmax over D=16 incident hyperedges ----------
__global__ __launch_bounds__(256) void node_attn_k(const u16* __restrict__ NE,
    const int* __restrict__ node_list, const float* __restrict__ snb,
    const float* __restrict__ ned, u16* __restrict__ NNo)
{
  const int lane = threadIdx.x & 63;
  const int n = blockIdx.x*4 + (threadIdx.x >> 6);
  int idx[D_DEG];
  float w[D_DEG];
  const float sb = snb[n];
  float mx = -1e30f;
  #pragma unroll
  for (int d=0; d<D_DEG; d++){
    idx[d] = node_list[n*D_DEG + d];
    float s = lrelu(sb + ned[idx[d]]);
    w[d] = s; mx = fmaxf(mx, s);
  }
  float sum = 0.f;
  #pragma unroll
  for (int d=0; d<D_DEG; d++){ w[d] = __expf(w[d]-mx); sum += w[d]; }
  const float inv = 1.f/sum;

  const int c = lane*4;
  float ax=0,ay=0,az=0,aw=0;
  #pragma unroll
  for (int d=0; d<D_DEG; d++){
    F4 h = load4(NE + (long)idx[d]*FEAT + c);
    float ww = w[d]*inv;
    ax += ww*h.x; ay += ww*h.y; az += ww*h.z; aw += ww*h.w;
  }
  F4 o; o.x=ax; o.y=ay; o.z=az; o.w=aw;
  store_bf4(NNo + (long)n*FEAT + c, o);
}

// ---------- final batch assembly — f32 output ----------
__global__ __launch_bounds__(256) void assemble_k(const u16* __restrict__ NNo,
    const u16* __restrict__ NE, const int* __restrict__ batch, float* __restrict__ out)
{
  const int b = blockIdx.x;
  const int j = threadIdx.x;
  int bi[7];
  #pragma unroll
  for (int s=0;s<7;s++) bi[s] = batch[b*7 + s];
  int right = 0;
  #pragma unroll
  for (int c=0;c<6;c++) if (bi[c] != 0) right = c+1;

  out[((long)b*7 + 0)*FEAT + j] = eluf(bf2f(NE[(long)bi[0]*FEAT + j]));

  #pragma unroll
  for (int s=1;s<7;s++){
    float val = 0.f;
    if (s < right) val = eluf(bf2f(NNo[(long)bi[s]*FEAT + j]));
    out[((long)b*7 + s)*FEAT + j] = val;
  }
}

extern "C" void kernel_launch(void* const* d_in, const int* in_sizes, int n_in,
                              void* d_out, int out_size, void* d_ws, size_t ws_size,
                              hipStream_t stream)
{
  const int*   batch      = (const int*)d_in[0];
  const float* node_embs  = (const float*)d_in[1];
  const float* edge_embs  = (const float*)d_in[2];
  const int*   edge_list  = (const int*)d_in[3];
  const int*   node_list  = (const int*)d_in[4];
  const float* Wn1 = (const float*)d_in[5];
  const float* We1 = (const float*)d_in[6];
  const float* ae1 = (const float*)d_in[7];
  const float* an1 = (const float*)d_in[8];
  const float* Wn2 = (const float*)d_in[9];
  const float* We2 = (const float*)d_in[10];
  const float* ae2 = (const float*)d_in[11];
  const float* an2 = (const float*)d_in[12];
  float* out = (float*)d_out;

  char* ws = (char*)d_ws;
  size_t off = 0;
  auto alloc = [&](size_t bytes)->void* {
    void* p = ws + off; off += (bytes + 255) & ~(size_t)255; return p;
  };
  u16* bHn = (u16*)alloc((size_t)N_NODES*FEAT*2);
  u16* bNE = (u16*)alloc((size_t)N_EDGES*FEAT*2);
  u16* bNN = (u16*)alloc((size_t)N_NODES*FEAT*2);
  u16* Wt1 = (u16*)alloc((size_t)FEAT*FEAT*2);
  u16* Wt2 = (u16*)alloc((size_t)FEAT*FEAT*2);
  float* hg  = (float*)alloc((size_t)N_NODES*4);
  float* snb = (float*)alloc((size_t)N_NODES*4);
  float* ned = (float*)alloc((size_t)N_EDGES*4);
  float* wE  = (float*)alloc(FEAT*4);

  dim3 blk(256);

  // weight transposes (tiny)
  wtrans_k<<<dim3(8,8), blk, 0, stream>>>(Wn1, Wt1);
  wtrans_k<<<dim3(8,8), blk, 0, stream>>>(Wn2, Wt2);

  // ---- layer 1 ----
  wvec_k<<<FEAT/4, blk, 0, stream>>>(We1, ae1, wE);                               // wE = We1 @ ae1_lo
  gemm_mfma_k<false,float><<<N_NODES/16, blk, 0, stream>>>(node_embs, Wt1,
      ae1+FEAT, an1, bHn, hg, snb);                                               // Hn1 + hg + snb
  edge_attn_k<float,false><<<N_EDGES/4, blk, 0, stream>>>(bHn, edge_embs, wE,
      edge_list, hg, an1+FEAT, bNE, ned);                                         // seb fused
  node_attn_k<<<N_NODES/4, blk, 0, stream>>>(bNE, node_list, snb, ned, bNN);

  // ---- layer 2 (ELU fused on loads) ----
  wvec_k<<<FEAT/4, blk, 0, stream>>>(We2, ae2, wE);                               // wE = We2 @ ae2_lo
  gemm_mfma_k<true,u16><<<N_NODES/16, blk, 0, stream>>>(bNN, Wt2,
      ae2+FEAT, an2, bHn, hg, snb);                                               // Hn2 = elu(NN1)@Wn2
  edge_attn_k<u16,true><<<N_EDGES/4, blk, 0, stream>>>(bHn, bNE, wE,
      edge_list, hg, an2+FEAT, bNE, ned);                                         // seb2 from elu(NE1), in-wave RAW safe
  node_attn_k<<<N_NODES/4, blk, 0, stream>>>(bNE, node_list, snb, ned, bNN);

  // ---- batch assembly (f32 out) ----
  assemble_k<<<BATCH, blk, 0, stream>>>(bNN, bNE, batch, out);
}

// Round 8
// 313.113 us; speedup vs baseline: 1.4090x; 1.1342x over previous
//
#include <hip/hip_runtime.h>
#include <stdint.h>

typedef unsigned short u16;
typedef unsigned int   u32;
typedef __attribute__((ext_vector_type(8))) short bf16x8;   // 8 bf16 (4 VGPRs)
typedef __attribute__((ext_vector_type(4))) float f32x4;    // MFMA C/D

#define N_NODES 30000
#define N_EDGES 60000
#define A_DEG   6
#define D_DEG   16
#define BATCH   4096
#define FEAT    256
#define APAD    8     // LDS pad: (256+8)*2 = 528 B row stride = 33*16 (keeps 16B align)

// ---------- bf16 helpers ----------
__device__ __forceinline__ float bfbits2f(u32 hi){ union{u32 u; float f;} v; v.u = hi; return v.f; }
__device__ __forceinline__ float bf2f(u16 h){ return bfbits2f(((u32)h)<<16); }
__device__ __forceinline__ u16 f2bf(float f){
  union{float f; u32 u;} v; v.f = f;
  u32 u = v.u;
  return (u16)((u + 0x7fffu + ((u>>16)&1u)) >> 16);   // RTNE
}

struct F4 { float x,y,z,w; };
struct F8 { float v[8]; };

__device__ __forceinline__ F4 load4(const float* p){
  float4 t = *reinterpret_cast<const float4*>(p);
  F4 f; f.x=t.x; f.y=t.y; f.z=t.z; f.w=t.w; return f;
}
__device__ __forceinline__ F4 load4(const u16* p){
  uint2 u = *reinterpret_cast<const uint2*>(p);
  F4 f;
  f.x = bfbits2f(u.x<<16);
  f.y = bfbits2f(u.x & 0xffff0000u);
  f.z = bfbits2f(u.y<<16);
  f.w = bfbits2f(u.y & 0xffff0000u);
  return f;
}
// 8-element load -> f32[8]
__device__ __forceinline__ F8 load8(const float* p){
  float4 a = *reinterpret_cast<const float4*>(p);
  float4 b = *reinterpret_cast<const float4*>(p+4);
  F8 f; f.v[0]=a.x; f.v[1]=a.y; f.v[2]=a.z; f.v[3]=a.w;
        f.v[4]=b.x; f.v[5]=b.y; f.v[6]=b.z; f.v[7]=b.w; return f;
}
__device__ __forceinline__ F8 load8(const u16* p){
  uint4 u = *reinterpret_cast<const uint4*>(p);
  F8 f;
  f.v[0]=bfbits2f(u.x<<16); f.v[1]=bfbits2f(u.x&0xffff0000u);
  f.v[2]=bfbits2f(u.y<<16); f.v[3]=bfbits2f(u.y&0xffff0000u);
  f.v[4]=bfbits2f(u.z<<16); f.v[5]=bfbits2f(u.z&0xffff0000u);
  f.v[6]=bfbits2f(u.w<<16); f.v[7]=bfbits2f(u.w&0xffff0000u);
  return f;
}
__device__ __forceinline__ void store_bf8(u16* p, const float* f){
  uint4 u;
  u.x = (u32)f2bf(f[0]) | ((u32)f2bf(f[1])<<16);
  u.y = (u32)f2bf(f[2]) | ((u32)f2bf(f[3])<<16);
  u.z = (u32)f2bf(f[4]) | ((u32)f2bf(f[5])<<16);
  u.w = (u32)f2bf(f[6]) | ((u32)f2bf(f[7])<<16);
  *reinterpret_cast<uint4*>(p) = u;
}

__device__ __forceinline__ float eluf(float x){ return x > 0.f ? x : (__expf(x) - 1.f); }
__device__ __forceinline__ float lrelu(float x){ return x > 0.f ? x : 0.2f*x; }

__device__ __forceinline__ float wave_sum_lane0(float v){
  #pragma unroll
  for (int off = 32; off > 0; off >>= 1) v += __shfl_down(v, off, 64);
  return v;
}
__device__ __forceinline__ float half_sum_all(float v){   // reduce within 32-lane half
  #pragma unroll
  for (int off = 1; off < 32; off <<= 1) v += __shfl_xor(v, off, 64);
  return v;
}

// ---------- weight transpose: Wt[n][k] = bf16(W[k][n]), 256x256 ----------
__global__ __launch_bounds__(256) void wtrans_k(const float* __restrict__ W,
                                                u16* __restrict__ Wt)
{
  __shared__ float T[32][33];
  const int bx = blockIdx.x;   // k-tile
  const int by = blockIdx.y;   // n-tile
  const int tc = threadIdx.x & 31;
  const int tr = threadIdx.x >> 5;
  #pragma unroll
  for (int i=0;i<4;i++){
    int r = tr + i*8;
    T[r][tc] = W[(bx*32 + r)*FEAT + by*32 + tc];
  }
  __syncthreads();
  #pragma unroll
  for (int i=0;i<4;i++){
    int r = tr + i*8;
    Wt[(by*32 + r)*FEAT + bx*32 + tc] = f2bf(T[tc][r]);
  }
}

// ---------- MFMA GEMM (64-row tile) + fused rowdots ----------
// Y[M,256](bf16) = act(X[M,256]) @ W via Wt[n][k] bf16.
// hg[row] = Y[row]·v1, snb[row] = Y[row]·v2.
// Block: 256 thr = 4 waves; tile 64 rows x 256 cols; wave w -> cols [w*64,w*64+64).
template<bool ELU, typename TIN>
__global__ __launch_bounds__(256) void gemm_mfma_k(
    const TIN* __restrict__ X, const u16* __restrict__ Wt,
    const float* __restrict__ v1, const float* __restrict__ v2,
    u16* __restrict__ Y, float* __restrict__ hg, float* __restrict__ snb,
    int M)
{
  __shared__ u16 As[64][FEAT + APAD];
  __shared__ float hgs[64], sns[64];
  const int tid = threadIdx.x;
  const long row0 = (long)blockIdx.x * 64;

  if (tid < 64){ hgs[tid] = 0.f; sns[tid] = 0.f; }

  // stage 64x256 X tile -> bf16 LDS (64 elems/thread)
  {
    const int c = (tid & 15) << 4;
    #pragma unroll
    for (int i=0;i<4;i++){
      const int r = (tid >> 4) + 16*i;
      u16* dst = &As[r][c];
      if (row0 + r < M){
        const TIN* src = X + (row0 + r)*FEAT + c;
        #pragma unroll
        for (int j=0;j<4;j++){
          F4 v = load4(src + 4*j);
          if (ELU){ v.x=eluf(v.x); v.y=eluf(v.y); v.z=eluf(v.z); v.w=eluf(v.w); }
          dst[4*j+0]=f2bf(v.x); dst[4*j+1]=f2bf(v.y);
          dst[4*j+2]=f2bf(v.z); dst[4*j+3]=f2bf(v.w);
        }
      } else {
        #pragma unroll
        for (int j=0;j<16;j++) dst[j] = 0;
      }
    }
  }
  __syncthreads();

  const int wave = tid >> 6;
  const int lane = tid & 63;
  const int l15  = lane & 15;
  const int kg   = lane >> 4;          // k-group 0..3

  f32x4 acc[4][4] = {};                // [row-tile][col-tile]

  for (int k0 = 0; k0 < FEAT; k0 += 32){
    bf16x8 a[4], b[4];
    #pragma unroll
    for (int rt=0;rt<4;rt++)
      a[rt] = *reinterpret_cast<const bf16x8*>(&As[rt*16 + l15][k0 + kg*8]);
    #pragma unroll
    for (int t=0;t<4;t++){
      const int n = wave*64 + t*16 + l15;
      b[t] = *reinterpret_cast<const bf16x8*>(Wt + (long)n*FEAT + k0 + kg*8);
    }
    #pragma unroll
    for (int rt=0;rt<4;rt++)
      #pragma unroll
      for (int t=0;t<4;t++)
        acc[rt][t] = __builtin_amdgcn_mfma_f32_16x16x32_bf16(a[rt], b[t], acc[rt][t], 0, 0, 0);
  }

  __syncthreads();   // done reading A-tile; reuse As for output staging

  // epilogue: stage Y + fused rowdots.  C/D: col=l15(+base), row=kg*4+reg
  float p1[4][4], p2[4][4];
  #pragma unroll
  for (int rt=0;rt<4;rt++)
    #pragma unroll
    for (int r=0;r<4;r++){ p1[rt][r]=0.f; p2[rt][r]=0.f; }

  #pragma unroll
  for (int t=0;t<4;t++){
    const int col = wave*64 + t*16 + l15;
    const float a1 = v1[col];
    const float a2 = v2[col];
    #pragma unroll
    for (int rt=0;rt<4;rt++){
      #pragma unroll
      for (int r=0;r<4;r++){
        const float val = acc[rt][t][r];
        As[rt*16 + kg*4 + r][col] = f2bf(val);
        p1[rt][r] += val * a1;
        p2[rt][r] += val * a2;
      }
    }
  }
  // reduce over the 16 lanes sharing kg
  #pragma unroll
  for (int off=1; off<16; off<<=1){
    #pragma unroll
    for (int rt=0;rt<4;rt++)
      #pragma unroll
      for (int r=0;r<4;r++){
        p1[rt][r] += __shfl_xor(p1[rt][r], off, 64);
        p2[rt][r] += __shfl_xor(p2[rt][r], off, 64);
      }
  }
  if (l15 == 0){
    #pragma unroll
    for (int rt=0;rt<4;rt++)
      #pragma unroll
      for (int r=0;r<4;r++){
        atomicAdd(&hgs[rt*16 + kg*4 + r], p1[rt][r]);
        atomicAdd(&sns[rt*16 + kg*4 + r], p2[rt][r]);
      }
  }
  __syncthreads();

  // coalesced store of Y tile (32 B/thread/row-group)
  {
    const int c = (tid & 15) << 4;
    #pragma unroll
    for (int i=0;i<4;i++){
      const int r = (tid >> 4) + 16*i;
      if (row0 + r < M){
        const uint4* s = reinterpret_cast<const uint4*>(&As[r][c]);
        uint4* d = reinterpret_cast<uint4*>(Y + (row0 + r)*FEAT + c);
        d[0] = s[0]; d[1] = s[1];
      }
    }
  }
  if (tid < 64 && row0 + tid < M){
    hg[row0 + tid]  = hgs[tid];
    snb[row0 + tid] = sns[tid];
  }
}

// ---------- wvec: wE[row] = W[row,:] · a[:]  (f32, 256 rows) ----------
__global__ __launch_bounds__(256) void wvec_k(const float* __restrict__ W,
    const float* __restrict__ a, float* __restrict__ wE)
{
  const int lane = threadIdx.x & 63;
  const int row  = blockIdx.x*4 + (threadIdx.x >> 6);
  const int c = lane*4;
  F4 h = load4(W + (long)row*FEAT + c);
  F4 v = load4(a + c);
  float p = h.x*v.x + h.y*v.y + h.z*v.z + h.w*v.w;
  p = wave_sum_lane0(p);
  if (lane == 0) wE[row] = p;
}

// ---------- edge attention (half-wave per edge, 16B loads) ----------
template<typename TIN, bool ELU>
__global__ __launch_bounds__(256) void edge_attn_k(const u16* __restrict__ Hn,
    const TIN* __restrict__ Xe, const float* __restrict__ wE,
    const int* __restrict__ edge_list,
    const float* __restrict__ hg, const float* __restrict__ an_hi,
    u16* __restrict__ NE, float* __restrict__ ned)
{
  const int tid = threadIdx.x;
  const int hl  = tid & 31;                 // lane within half-wave
  const int e   = blockIdx.x*8 + (tid >> 5);
  const int c   = hl*8;

  // fused seb = act(Xe[e]) · wE
  float sb;
  {
    F8 x = load8(Xe + (long)e*FEAT + c);
    if (ELU){
      #pragma unroll
      for (int j=0;j<8;j++) x.v[j] = eluf(x.v[j]);
    }
    F8 v = load8(wE + c);
    float p = 0.f;
    #pragma unroll
    for (int j=0;j<8;j++) p += x.v[j]*v.v[j];
    sb = half_sum_all(p);
  }

  int idx[A_DEG];
  float w[A_DEG];
  float mx = -1e30f;
  #pragma unroll
  for (int a=0;a<A_DEG;a++){
    idx[a] = edge_list[e*A_DEG + a];
    float s = lrelu(sb + hg[idx[a]]);
    w[a] = s; mx = fmaxf(mx, s);
  }
  float sum = 0.f;
  #pragma unroll
  for (int a=0;a<A_DEG;a++){ w[a] = __expf(w[a]-mx); sum += w[a]; }
  const float inv = 1.f/sum;

  float o[8] = {};
  #pragma unroll
  for (int a=0;a<A_DEG;a++){
    F8 h = load8(Hn + (long)idx[a]*FEAT + c);
    const float ww = w[a]*inv;
    #pragma unroll
    for (int j=0;j<8;j++) o[j] += ww*h.v[j];
  }
  store_bf8(NE + (long)e*FEAT + c, o);

  F8 v = load8(an_hi + c);
  float p = 0.f;
  #pragma unroll
  for (int j=0;j<8;j++) p += o[j]*v.v[j];
  p = half_sum_all(p);
  if (hl == 0) ned[e] = p;
}

// ---------- node attention (half-wave per node, 16B loads) ----------
__global__ __launch_bounds__(256) void node_attn_k(const u16* __restrict__ NE,
    const int* __restrict__ node_list, const float* __restrict__ snb,
    const float* __restrict__ ned, u16* __restrict__ NNo)
{
  const int tid = threadIdx.x;
  const int hl  = tid & 31;
  const int n   = blockIdx.x*8 + (tid >> 5);
  const int c   = hl*8;

  int idx[D_DEG];
  float w[D_DEG];
  const float sb = snb[n];
  float mx = -1e30f;
  #pragma unroll
  for (int d=0; d<D_DEG; d++){
    idx[d] = node_list[n*D_DEG + d];
    float s = lrelu(sb + ned[idx[d]]);
    w[d] = s; mx = fmaxf(mx, s);
  }
  float sum = 0.f;
  #pragma unroll
  for (int d=0; d<D_DEG; d++){ w[d] = __expf(w[d]-mx); sum += w[d]; }
  const float inv = 1.f/sum;

  float o[8] = {};
  #pragma unroll
  for (int d=0; d<D_DEG; d++){
    F8 h = load8(NE + (long)idx[d]*FEAT + c);
    const float ww = w[d]*inv;
    #pragma unroll
    for (int j=0;j<8;j++) o[j] += ww*h.v[j];
  }
  store_bf8(NNo + (long)n*FEAT + c, o);
}

// ---------- final batch assembly — f32 output ----------
__global__ __launch_bounds__(256) void assemble_k(const u16* __restrict__ NNo,
    const u16* __restrict__ NE, const int* __restrict__ batch, float* __restrict__ out)
{
  const int b = blockIdx.x;
  const int j = threadIdx.x;
  int bi[7];
  #pragma unroll
  for (int s=0;s<7;s++) bi[s] = batch[b*7 + s];
  int right = 0;
  #pragma unroll
  for (int c=0;c<6;c++) if (bi[c] != 0) right = c+1;

  out[((long)b*7 + 0)*FEAT + j] = eluf(bf2f(NE[(long)bi[0]*FEAT + j]));

  #pragma unroll
  for (int s=1;s<7;s++){
    float val = 0.f;
    if (s < right) val = eluf(bf2f(NNo[(long)bi[s]*FEAT + j]));
    out[((long)b*7 + s)*FEAT + j] = val;
  }
}

extern "C" void kernel_launch(void* const* d_in, const int* in_sizes, int n_in,
                              void* d_out, int out_size, void* d_ws, size_t ws_size,
                              hipStream_t stream)
{
  const int*   batch      = (const int*)d_in[0];
  const float* node_embs  = (const float*)d_in[1];
  const float* edge_embs  = (const float*)d_in[2];
  const int*   edge_list  = (const int*)d_in[3];
  const int*   node_list  = (const int*)d_in[4];
  const float* Wn1 = (const float*)d_in[5];
  const float* We1 = (const float*)d_in[6];
  const float* ae1 = (const float*)d_in[7];
  const float* an1 = (const float*)d_in[8];
  const float* Wn2 = (const float*)d_in[9];
  const float* We2 = (const float*)d_in[10];
  const float* ae2 = (const float*)d_in[11];
  const float* an2 = (const float*)d_in[12];
  float* out = (float*)d_out;

  char* ws = (char*)d_ws;
  size_t off = 0;
  auto alloc = [&](size_t bytes)->void* {
    void* p = ws + off; off += (bytes + 255) & ~(size_t)255; return p;
  };
  u16* bHn = (u16*)alloc((size_t)N_NODES*FEAT*2);
  u16* bNE = (u16*)alloc((size_t)N_EDGES*FEAT*2);
  u16* bNN = (u16*)alloc((size_t)N_NODES*FEAT*2);
  u16* Wt1 = (u16*)alloc((size_t)FEAT*FEAT*2);
  u16* Wt2 = (u16*)alloc((size_t)FEAT*FEAT*2);
  float* hg  = (float*)alloc((size_t)N_NODES*4);
  float* snb = (float*)alloc((size_t)N_NODES*4);
  float* ned = (float*)alloc((size_t)N_EDGES*4);
  float* wE  = (float*)alloc(FEAT*4);

  dim3 blk(256);
  const int gemm_grid = (N_NODES + 63) / 64;

  wtrans_k<<<dim3(8,8), blk, 0, stream>>>(Wn1, Wt1);
  wtrans_k<<<dim3(8,8), blk, 0, stream>>>(Wn2, Wt2);

  // ---- layer 1 ----
  wvec_k<<<FEAT/4, blk, 0, stream>>>(We1, ae1, wE);
  gemm_mfma_k<false,float><<<gemm_grid, blk, 0, stream>>>(node_embs, Wt1,
      ae1+FEAT, an1, bHn, hg, snb, N_NODES);
  edge_attn_k<float,false><<<N_EDGES/8, blk, 0, stream>>>(bHn, edge_embs, wE,
      edge_list, hg, an1+FEAT, bNE, ned);
  node_attn_k<<<N_NODES/8, blk, 0, stream>>>(bNE, node_list, snb, ned, bNN);

  // ---- layer 2 (ELU fused on loads) ----
  wvec_k<<<FEAT/4, blk, 0, stream>>>(We2, ae2, wE);
  gemm_mfma_k<true,u16><<<gemm_grid, blk, 0, stream>>>(bNN, Wt2,
      ae2+FEAT, an2, bHn, hg, snb, N_NODES);
  edge_attn_k<u16,true><<<N_EDGES/8, blk, 0, stream>>>(bHn, bNE, wE,
      edge_list, hg, an2+FEAT, bNE, ned);
  node_attn_k<<<N_NODES/8, blk, 0, stream>>>(bNE, node_list, snb, ned, bNN);

  // ---- batch assembly (f32 out) ----
  assemble_k<<<BATCH, blk, 0, stream>>>(bNN, bNE, batch, out);
}

// Round 9
// 301.520 us; speedup vs baseline: 1.4632x; 1.0384x over previous
//
#include <hip/hip_runtime.h>
#include <stdint.h>

typedef unsigned short u16;
typedef unsigned int   u32;
typedef __attribute__((ext_vector_type(8))) short bf16x8;   // 8 bf16 (4 VGPRs)
typedef __attribute__((ext_vector_type(4))) float f32x4;    // MFMA C/D

#define N_NODES 30000
#define N_EDGES 60000
#define A_DEG   6
#define D_DEG   16
#define BATCH   4096
#define FEAT    256
#define APAD    8     // LDS pad: (256+8)*2 = 528 B row stride (16B-aligned)

// ---------- bf16 helpers ----------
__device__ __forceinline__ float bfbits2f(u32 hi){ union{u32 u; float f;} v; v.u = hi; return v.f; }
__device__ __forceinline__ float bf2f(u16 h){ return bfbits2f(((u32)h)<<16); }
__device__ __forceinline__ u16 f2bf(float f){
  union{float f; u32 u;} v; v.f = f;
  u32 u = v.u;
  return (u16)((u + 0x7fffu + ((u>>16)&1u)) >> 16);   // RTNE
}

struct F4 { float x,y,z,w; };
struct F8 { float v[8]; };

__device__ __forceinline__ F4 load4(const float* p){
  float4 t = *reinterpret_cast<const float4*>(p);
  F4 f; f.x=t.x; f.y=t.y; f.z=t.z; f.w=t.w; return f;
}
__device__ __forceinline__ F4 load4(const u16* p){
  uint2 u = *reinterpret_cast<const uint2*>(p);
  F4 f;
  f.x = bfbits2f(u.x<<16);
  f.y = bfbits2f(u.x & 0xffff0000u);
  f.z = bfbits2f(u.y<<16);
  f.w = bfbits2f(u.y & 0xffff0000u);
  return f;
}
__device__ __forceinline__ F8 load8(const float* p){
  float4 a = *reinterpret_cast<const float4*>(p);
  float4 b = *reinterpret_cast<const float4*>(p+4);
  F8 f; f.v[0]=a.x; f.v[1]=a.y; f.v[2]=a.z; f.v[3]=a.w;
        f.v[4]=b.x; f.v[5]=b.y; f.v[6]=b.z; f.v[7]=b.w; return f;
}
__device__ __forceinline__ F8 load8(const u16* p){
  uint4 u = *reinterpret_cast<const uint4*>(p);
  F8 f;
  f.v[0]=bfbits2f(u.x<<16); f.v[1]=bfbits2f(u.x&0xffff0000u);
  f.v[2]=bfbits2f(u.y<<16); f.v[3]=bfbits2f(u.y&0xffff0000u);
  f.v[4]=bfbits2f(u.z<<16); f.v[5]=bfbits2f(u.z&0xffff0000u);
  f.v[6]=bfbits2f(u.w<<16); f.v[7]=bfbits2f(u.w&0xffff0000u);
  return f;
}
__device__ __forceinline__ void store_bf8(u16* p, const float* f){
  uint4 u;
  u.x = (u32)f2bf(f[0]) | ((u32)f2bf(f[1])<<16);
  u.y = (u32)f2bf(f[2]) | ((u32)f2bf(f[3])<<16);
  u.z = (u32)f2bf(f[4]) | ((u32)f2bf(f[5])<<16);
  u.w = (u32)f2bf(f[6]) | ((u32)f2bf(f[7])<<16);
  *reinterpret_cast<uint4*>(p) = u;
}

__device__ __forceinline__ float eluf(float x){ return x > 0.f ? x : (__expf(x) - 1.f); }
__device__ __forceinline__ float lrelu(float x){ return x > 0.f ? x : 0.2f*x; }

__device__ __forceinline__ float wave_sum_lane0(float v){
  #pragma unroll
  for (int off = 32; off > 0; off >>= 1) v += __shfl_down(v, off, 64);
  return v;
}
__device__ __forceinline__ float half_sum_all(float v){   // reduce within 32-lane half
  #pragma unroll
  for (int off = 1; off < 32; off <<= 1) v += __shfl_xor(v, off, 64);
  return v;
}

// ---------- weight transpose (both weights, z = which): Wt[n][k] = bf16(W[k][n]) ----------
__global__ __launch_bounds__(256) void wtrans_k(const float* __restrict__ W1,
    u16* __restrict__ Wt1, const float* __restrict__ W2, u16* __restrict__ Wt2)
{
  const float* W = blockIdx.z ? W2 : W1;
  u16* Wt        = blockIdx.z ? Wt2 : Wt1;
  __shared__ float T[32][33];
  const int bx = blockIdx.x;   // k-tile
  const int by = blockIdx.y;   // n-tile
  const int tc = threadIdx.x & 31;
  const int tr = threadIdx.x >> 5;
  #pragma unroll
  for (int i=0;i<4;i++){
    int r = tr + i*8;
    T[r][tc] = W[(bx*32 + r)*FEAT + by*32 + tc];
  }
  __syncthreads();
  #pragma unroll
  for (int i=0;i<4;i++){
    int r = tr + i*8;
    Wt[(by*32 + r)*FEAT + bx*32 + tc] = f2bf(T[tc][r]);
  }
}

// ---------- wvec (both layers in one launch): wE[row] = W[row,:] · a[:] ----------
__global__ __launch_bounds__(256) void wvec_k(
    const float* __restrict__ W1, const float* __restrict__ a1, float* __restrict__ o1,
    const float* __restrict__ W2, const float* __restrict__ a2, float* __restrict__ o2)
{
  const int sel  = blockIdx.x >> 6;            // 0..1
  const float* W = sel ? W2 : W1;
  const float* a = sel ? a2 : a1;
  float* o       = sel ? o2 : o1;
  const int lane = threadIdx.x & 63;
  const int row  = (blockIdx.x & 63)*4 + (threadIdx.x >> 6);
  const int c = lane*4;
  F4 h = load4(W + (long)row*FEAT + c);
  F4 v = load4(a + c);
  float p = wave_sum_lane0(h.x*v.x + h.y*v.y + h.z*v.z + h.w*v.w);
  if (lane == 0) o[row] = p;
}

// ---------- MFMA GEMM (64-row tile) + fused rowdots ----------
// Y[M,256](bf16) = act(X[M,256]) @ W via Wt[n][k]; hg=Y·v1, snb=Y·v2.
template<bool ELU, typename TIN>
__global__ __launch_bounds__(256) void gemm_mfma_k(
    const TIN* __restrict__ X, const u16* __restrict__ Wt,
    const float* __restrict__ v1, const float* __restrict__ v2,
    u16* __restrict__ Y, float* __restrict__ hg, float* __restrict__ snb,
    int M)
{
  __shared__ u16 As[64][FEAT + APAD];
  __shared__ float hgs[64], sns[64];
  const int tid = threadIdx.x;
  const long row0 = (long)blockIdx.x * 64;

  if (tid < 64){ hgs[tid] = 0.f; sns[tid] = 0.f; }

  {
    const int c = (tid & 15) << 4;
    #pragma unroll
    for (int i=0;i<4;i++){
      const int r = (tid >> 4) + 16*i;
      u16* dst = &As[r][c];
      if (row0 + r < M){
        const TIN* src = X + (row0 + r)*FEAT + c;
        #pragma unroll
        for (int j=0;j<4;j++){
          F4 v = load4(src + 4*j);
          if (ELU){ v.x=eluf(v.x); v.y=eluf(v.y); v.z=eluf(v.z); v.w=eluf(v.w); }
          dst[4*j+0]=f2bf(v.x); dst[4*j+1]=f2bf(v.y);
          dst[4*j+2]=f2bf(v.z); dst[4*j+3]=f2bf(v.w);
        }
      } else {
        #pragma unroll
        for (int j=0;j<16;j++) dst[j] = 0;
      }
    }
  }
  __syncthreads();

  const int wave = tid >> 6;
  const int lane = tid & 63;
  const int l15  = lane & 15;
  const int kg   = lane >> 4;

  f32x4 acc[4][4] = {};

  for (int k0 = 0; k0 < FEAT; k0 += 32){
    bf16x8 a[4], b[4];
    #pragma unroll
    for (int rt=0;rt<4;rt++)
      a[rt] = *reinterpret_cast<const bf16x8*>(&As[rt*16 + l15][k0 + kg*8]);
    #pragma unroll
    for (int t=0;t<4;t++){
      const int n = wave*64 + t*16 + l15;
      b[t] = *reinterpret_cast<const bf16x8*>(Wt + (long)n*FEAT + k0 + kg*8);
    }
    #pragma unroll
    for (int rt=0;rt<4;rt++)
      #pragma unroll
      for (int t=0;t<4;t++)
        acc[rt][t] = __builtin_amdgcn_mfma_f32_16x16x32_bf16(a[rt], b[t], acc[rt][t], 0, 0, 0);
  }

  __syncthreads();

  float p1[4][4] = {}, p2[4][4] = {};
  #pragma unroll
  for (int t=0;t<4;t++){
    const int col = wave*64 + t*16 + l15;
    const float a1 = v1[col];
    const float a2 = v2[col];
    #pragma unroll
    for (int rt=0;rt<4;rt++){
      #pragma unroll
      for (int r=0;r<4;r++){
        const float val = acc[rt][t][r];
        As[rt*16 + kg*4 + r][col] = f2bf(val);
        p1[rt][r] += val * a1;
        p2[rt][r] += val * a2;
      }
    }
  }
  #pragma unroll
  for (int off=1; off<16; off<<=1){
    #pragma unroll
    for (int rt=0;rt<4;rt++)
      #pragma unroll
      for (int r=0;r<4;r++){
        p1[rt][r] += __shfl_xor(p1[rt][r], off, 64);
        p2[rt][r] += __shfl_xor(p2[rt][r], off, 64);
      }
  }
  if (l15 == 0){
    #pragma unroll
    for (int rt=0;rt<4;rt++)
      #pragma unroll
      for (int r=0;r<4;r++){
        atomicAdd(&hgs[rt*16 + kg*4 + r], p1[rt][r]);
        atomicAdd(&sns[rt*16 + kg*4 + r], p2[rt][r]);
      }
  }
  __syncthreads();

  {
    const int c = (tid & 15) << 4;
    #pragma unroll
    for (int i=0;i<4;i++){
      const int r = (tid >> 4) + 16*i;
      if (row0 + r < M){
        const uint4* s = reinterpret_cast<const uint4*>(&As[r][c]);
        uint4* d = reinterpret_cast<uint4*>(Y + (row0 + r)*FEAT + c);
        d[0] = s[0]; d[1] = s[1];
      }
    }
  }
  if (tid < 64 && row0 + tid < M){
    hg[row0 + tid]  = hgs[tid];
    snb[row0 + tid] = sns[tid];
  }
}

// ---------- FUSED node_attn(L1) + gemm(L2) ----------
// Phase 1: NN[n] = softmax-attn over D=16 NE rows; elu; bf16 -> LDS A-tile.
// Phase 2: Hn2 = NN @ Wn2 (MFMA) + fused rowdots (hg, snb for layer 2).
// snb1 is read only for this block's own rows before snb2 overwrites them.
__global__ __launch_bounds__(256) void node_gemm_k(
    const u16* __restrict__ NE, const int* __restrict__ node_list,
    const float* __restrict__ snb1, const float* __restrict__ ned,
    const u16* __restrict__ Wt,
    const float* __restrict__ v1, const float* __restrict__ v2,
    u16* __restrict__ Y, float* __restrict__ hg, float* __restrict__ snb2,
    int M)
{
  __shared__ u16 As[64][FEAT + APAD];
  __shared__ float hgs[64], sns[64];
  const int tid = threadIdx.x;
  const long row0 = (long)blockIdx.x * 64;

  if (tid < 64){ hgs[tid] = 0.f; sns[tid] = 0.f; }

  // ---- phase 1: gather-attention into LDS ----
  const int hw = tid >> 5;      // half-wave 0..7
  const int hl = tid & 31;
  const int c  = hl*8;
  #pragma unroll
  for (int i=0;i<8;i++){
    const int r = hw*8 + i;
    const long n = row0 + r;
    u16* dst = &As[r][c];
    if (n < M){
      int idx[D_DEG];
      float w[D_DEG];
      const float sb = snb1[n];
      float mx = -1e30f;
      #pragma unroll
      for (int d=0; d<D_DEG; d++){
        idx[d] = node_list[n*D_DEG + d];
        float s = lrelu(sb + ned[idx[d]]);
        w[d] = s; mx = fmaxf(mx, s);
      }
      float sum = 0.f;
      #pragma unroll
      for (int d=0; d<D_DEG; d++){ w[d] = __expf(w[d]-mx); sum += w[d]; }
      const float inv = 1.f/sum;

      float o[8] = {};
      #pragma unroll
      for (int d=0; d<D_DEG; d++){
        F8 h = load8(NE + (long)idx[d]*FEAT + c);
        const float ww = w[d]*inv;
        #pragma unroll
        for (int j=0;j<8;j++) o[j] += ww*h.v[j];
      }
      // apply ELU (layer-2 input activation), convert to bf16
      #pragma unroll
      for (int j=0;j<8;j++) dst[j] = f2bf(eluf(o[j]));
    } else {
      #pragma unroll
      for (int j=0;j<8;j++) dst[j] = 0;
    }
  }
  __syncthreads();

  // ---- phase 2: MFMA ----
  const int wave = tid >> 6;
  const int lane = tid & 63;
  const int l15  = lane & 15;
  const int kg   = lane >> 4;

  f32x4 acc[4][4] = {};

  for (int k0 = 0; k0 < FEAT; k0 += 32){
    bf16x8 a[4], b[4];
    #pragma unroll
    for (int rt=0;rt<4;rt++)
      a[rt] = *reinterpret_cast<const bf16x8*>(&As[rt*16 + l15][k0 + kg*8]);
    #pragma unroll
    for (int t=0;t<4;t++){
      const int n = wave*64 + t*16 + l15;
      b[t] = *reinterpret_cast<const bf16x8*>(Wt + (long)n*FEAT + k0 + kg*8);
    }
    #pragma unroll
    for (int rt=0;rt<4;rt++)
      #pragma unroll
      for (int t=0;t<4;t++)
        acc[rt][t] = __builtin_amdgcn_mfma_f32_16x16x32_bf16(a[rt], b[t], acc[rt][t], 0, 0, 0);
  }

  __syncthreads();

  float p1[4][4] = {}, p2[4][4] = {};
  #pragma unroll
  for (int t=0;t<4;t++){
    const int col = wave*64 + t*16 + l15;
    const float a1 = v1[col];
    const float a2 = v2[col];
    #pragma unroll
    for (int rt=0;rt<4;rt++){
      #pragma unroll
      for (int r=0;r<4;r++){
        const float val = acc[rt][t][r];
        As[rt*16 + kg*4 + r][col] = f2bf(val);
        p1[rt][r] += val * a1;
        p2[rt][r] += val * a2;
      }
    }
  }
  #pragma unroll
  for (int off=1; off<16; off<<=1){
    #pragma unroll
    for (int rt=0;rt<4;rt++)
      #pragma unroll
      for (int r=0;r<4;r++){
        p1[rt][r] += __shfl_xor(p1[rt][r], off, 64);
        p2[rt][r] += __shfl_xor(p2[rt][r], off, 64);
      }
  }
  if (l15 == 0){
    #pragma unroll
    for (int rt=0;rt<4;rt++)
      #pragma unroll
      for (int r=0;r<4;r++){
        atomicAdd(&hgs[rt*16 + kg*4 + r], p1[rt][r]);
        atomicAdd(&sns[rt*16 + kg*4 + r], p2[rt][r]);
      }
  }
  __syncthreads();

  {
    const int cc = (tid & 15) << 4;
    #pragma unroll
    for (int i=0;i<4;i++){
      const int r = (tid >> 4) + 16*i;
      if (row0 + r < M){
        const uint4* s = reinterpret_cast<const uint4*>(&As[r][cc]);
        uint4* d = reinterpret_cast<uint4*>(Y + (row0 + r)*FEAT + cc);
        d[0] = s[0]; d[1] = s[1];
      }
    }
  }
  if (tid < 64 && row0 + tid < M){
    hg[row0 + tid]   = hgs[tid];
    snb2[row0 + tid] = sns[tid];
  }
}

// ---------- edge attention (half-wave per edge, 16B loads, fused seb) ----------
template<typename TIN, bool ELU>
__global__ __launch_bounds__(256) void edge_attn_k(const u16* __restrict__ Hn,
    const TIN* __restrict__ Xe, const float* __restrict__ wE,
    const int* __restrict__ edge_list,
    const float* __restrict__ hg, const float* __restrict__ an_hi,
    u16* __restrict__ NE, float* __restrict__ ned)
{
  const int tid = threadIdx.x;
  const int hl  = tid & 31;
  const int e   = blockIdx.x*8 + (tid >> 5);
  const int c   = hl*8;

  float sb;
  {
    F8 x = load8(Xe + (long)e*FEAT + c);
    if (ELU){
      #pragma unroll
      for (int j=0;j<8;j++) x.v[j] = eluf(x.v[j]);
    }
    F8 v = load8(wE + c);
    float p = 0.f;
    #pragma unroll
    for (int j=0;j<8;j++) p += x.v[j]*v.v[j];
    sb = half_sum_all(p);
  }

  int idx[A_DEG];
  float w[A_DEG];
  float mx = -1e30f;
  #pragma unroll
  for (int a=0;a<A_DEG;a++){
    idx[a] = edge_list[e*A_DEG + a];
    float s = lrelu(sb + hg[idx[a]]);
    w[a] = s; mx = fmaxf(mx, s);
  }
  float sum = 0.f;
  #pragma unroll
  for (int a=0;a<A_DEG;a++){ w[a] = __expf(w[a]-mx); sum += w[a]; }
  const float inv = 1.f/sum;

  float o[8] = {};
  #pragma unroll
  for (int a=0;a<A_DEG;a++){
    F8 h = load8(Hn + (long)idx[a]*FEAT + c);
    const float ww = w[a]*inv;
    #pragma unroll
    for (int j=0;j<8;j++) o[j] += ww*h.v[j];
  }
  store_bf8(NE + (long)e*FEAT + c, o);

  F8 v = load8(an_hi + c);
  float p = 0.f;
  #pragma unroll
  for (int j=0;j<8;j++) p += o[j]*v.v[j];
  p = half_sum_all(p);
  if (hl == 0) ned[e] = p;
}

// ---------- node attention L2 (half-wave per node) ----------
__global__ __launch_bounds__(256) void node_attn_k(const u16* __restrict__ NE,
    const int* __restrict__ node_list, const float* __restrict__ snb,
    const float* __restrict__ ned, u16* __restrict__ NNo)
{
  const int tid = threadIdx.x;
  const int hl  = tid & 31;
  const int n   = blockIdx.x*8 + (tid >> 5);
  const int c   = hl*8;

  int idx[D_DEG];
  float w[D_DEG];
  const float sb = snb[n];
  float mx = -1e30f;
  #pragma unroll
  for (int d=0; d<D_DEG; d++){
    idx[d] = node_list[n*D_DEG + d];
    float s = lrelu(sb + ned[idx[d]]);
    w[d] = s; mx = fmaxf(mx, s);
  }
  float sum = 0.f;
  #pragma unroll
  for (int d=0; d<D_DEG; d++){ w[d] = __expf(w[d]-mx); sum += w[d]; }
  const float inv = 1.f/sum;

  float o[8] = {};
  #pragma unroll
  for (int d=0; d<D_DEG; d++){
    F8 h = load8(NE + (long)idx[d]*FEAT + c);
    const float ww = w[d]*inv;
    #pragma unroll
    for (int j=0;j<8;j++) o[j] += ww*h.v[j];
  }
  store_bf8(NNo + (long)n*FEAT + c, o);
}

// ---------- final batch assembly — f32 output ----------
__global__ __launch_bounds__(256) void assemble_k(const u16* __restrict__ NNo,
    const u16* __restrict__ NE, const int* __restrict__ batch, float* __restrict__ out)
{
  const int b = blockIdx.x;
  const int j = threadIdx.x;
  int bi[7];
  #pragma unroll
  for (int s=0;s<7;s++) bi[s] = batch[b*7 + s];
  int right = 0;
  #pragma unroll
  for (int c=0;c<6;c++) if (bi[c] != 0) right = c+1;

  out[((long)b*7 + 0)*FEAT + j] = eluf(bf2f(NE[(long)bi[0]*FEAT + j]));

  #pragma unroll
  for (int s=1;s<7;s++){
    float val = 0.f;
    if (s < right) val = eluf(bf2f(NNo[(long)bi[s]*FEAT + j]));
    out[((long)b*7 + s)*FEAT + j] = val;
  }
}

extern "C" void kernel_launch(void* const* d_in, const int* in_sizes, int n_in,
                              void* d_out, int out_size, void* d_ws, size_t ws_size,
                              hipStream_t stream)
{
  const int*   batch      = (const int*)d_in[0];
  const float* node_embs  = (const float*)d_in[1];
  const float* edge_embs  = (const float*)d_in[2];
  const int*   edge_list  = (const int*)d_in[3];
  const int*   node_list  = (const int*)d_in[4];
  const float* Wn1 = (const float*)d_in[5];
  const float* We1 = (const float*)d_in[6];
  const float* ae1 = (const float*)d_in[7];
  const float* an1 = (const float*)d_in[8];
  const float* Wn2 = (const float*)d_in[9];
  const float* We2 = (const float*)d_in[10];
  const float* ae2 = (const float*)d_in[11];
  const float* an2 = (const float*)d_in[12];
  float* out = (float*)d_out;

  char* ws = (char*)d_ws;
  size_t off = 0;
  auto alloc = [&](size_t bytes)->void* {
    void* p = ws + off; off += (bytes + 255) & ~(size_t)255; return p;
  };
  u16* bHn = (u16*)alloc((size_t)N_NODES*FEAT*2);
  u16* bNE = (u16*)alloc((size_t)N_EDGES*FEAT*2);
  u16* bNN = (u16*)alloc((size_t)N_NODES*FEAT*2);
  u16* Wt1 = (u16*)alloc((size_t)FEAT*FEAT*2);
  u16* Wt2 = (u16*)alloc((size_t)FEAT*FEAT*2);
  float* hg  = (float*)alloc((size_t)N_NODES*4);
  float* snb = (float*)alloc((size_t)N_NODES*4);
  float* ned = (float*)alloc((size_t)N_EDGES*4);
  float* wE1 = (float*)alloc(FEAT*4);
  float* wE2 = (float*)alloc(FEAT*4);

  dim3 blk(256);
  const int gemm_grid = (N_NODES + 63) / 64;

  // prep: both transposes, both wvecs (2 launches)
  wtrans_k<<<dim3(8,8,2), blk, 0, stream>>>(Wn1, Wt1, Wn2, Wt2);
  wvec_k<<<128, blk, 0, stream>>>(We1, ae1, wE1, We2, ae2, wE2);

  // ---- layer 1 ----
  gemm_mfma_k<false,float><<<gemm_grid, blk, 0, stream>>>(node_embs, Wt1,
      ae1+FEAT, an1, bHn, hg, snb, N_NODES);
  edge_attn_k<float,false><<<N_EDGES/8, blk, 0, stream>>>(bHn, edge_embs, wE1,
      edge_list, hg, an1+FEAT, bNE, ned);

  // ---- fused: node_attn(L1) + gemm(L2) ----
  node_gemm_k<<<gemm_grid, blk, 0, stream>>>(bNE, node_list, snb, ned,
      Wt2, ae2+FEAT, an2, bHn, hg, snb, N_NODES);

  // ---- layer 2 attention ----
  edge_attn_k<u16,true><<<N_EDGES/8, blk, 0, stream>>>(bHn, bNE, wE2,
      edge_list, hg, an2+FEAT, bNE, ned);
  node_attn_k<<<N_NODES/8, blk, 0, stream>>>(bNE, node_list, snb, ned, bNN);

  // ---- batch assembly (f32 out) ----
  assemble_k<<<BATCH, blk, 0, stream>>>(bNN, bNE, batch, out);
}